// Round 1
// baseline (3226.178 us; speedup 1.0000x reference)
//
#include <hip/hip_runtime.h>

#define N_CONS 100000
#define N_VAR  200000
#define N_EDGE 2000000
#define EMB 64

// ---------------- CSR build ----------------

__global__ __launch_bounds__(256) void count_deg(const int* __restrict__ row,
                                                 const int* __restrict__ col,
                                                 int* __restrict__ degV,
                                                 int* __restrict__ degC, int E) {
  int stride = gridDim.x * blockDim.x;
  for (int e = blockIdx.x * blockDim.x + threadIdx.x; e < E; e += stride) {
    atomicAdd(&degV[col[e]], 1);
    atomicAdd(&degC[row[e]], 1);
  }
}

// In-place exclusive scan of a[0..n) -> offsets, writes a[n]=total.
// One block per array; block 0 handles (offV,nV), block 1 handles (offC,nC).
__global__ __launch_bounds__(256) void scan2(int* __restrict__ offV, int nV,
                                             int* __restrict__ offC, int nC) {
  int* a = (blockIdx.x == 0) ? offV : offC;
  int n  = (blockIdx.x == 0) ? nV : nC;
  __shared__ int s[256];
  int t = threadIdx.x;
  int chunk = (n + 255) / 256;
  int lo = t * chunk;
  int hi = lo + chunk;
  if (lo > n) lo = n;
  if (hi > n) hi = n;
  int sum = 0;
  for (int i = lo; i < hi; ++i) sum += a[i];
  s[t] = sum;
  __syncthreads();
  // Hillis-Steele inclusive scan in LDS
  for (int d = 1; d < 256; d <<= 1) {
    int v = (t >= d) ? s[t - d] : 0;
    __syncthreads();
    s[t] += v;
    __syncthreads();
  }
  int run = s[t] - sum;  // exclusive prefix for this thread's chunk
  for (int i = lo; i < hi; ++i) {
    int dv = a[i];
    a[i] = run;
    run += dv;
  }
  if (t == 255) a[n] = s[255];
}

__global__ __launch_bounds__(256) void scatter_adj(const int* __restrict__ row,
                                                   const int* __restrict__ col,
                                                   int* __restrict__ curV,
                                                   int* __restrict__ curC,
                                                   int* __restrict__ adjV,
                                                   int* __restrict__ adjC, int E) {
  int stride = gridDim.x * blockDim.x;
  for (int e = blockIdx.x * blockDim.x + threadIdx.x; e < E; e += stride) {
    int r = row[e], c = col[e];
    int p = atomicAdd(&curV[c], 1);
    adjV[p] = r;
    int q = atomicAdd(&curC[r], 1);
    adjC[q] = c;
  }
}

// ---------------- Embedding MLP: relu(relu(pn(x)@W1+b1)@W2+b2) [+ bi*breakW] ----------------

template <int F>
__global__ __launch_bounds__(256) void embed_kernel(
    const float* __restrict__ x, const float* __restrict__ shift,
    const float* __restrict__ scale, const float* __restrict__ W1,
    const float* __restrict__ b1, const float* __restrict__ W2,
    const float* __restrict__ b2, const float* __restrict__ bi,
    const float* __restrict__ bW, float* __restrict__ out, int n) {
  __shared__ float W1s[F * 64];
  __shared__ float W2s[64 * 64];
  __shared__ float b1s[64], b2s[64], bWs[64];
  __shared__ float shs[32], scs[32];
  for (int i = threadIdx.x; i < F * 64; i += blockDim.x) W1s[i] = W1[i];
  for (int i = threadIdx.x; i < 64 * 64; i += blockDim.x) W2s[i] = W2[i];
  if (threadIdx.x < 64) {
    b1s[threadIdx.x] = b1[threadIdx.x];
    b2s[threadIdx.x] = b2[threadIdx.x];
    bWs[threadIdx.x] = bW ? bW[threadIdx.x] : 0.f;
  }
  if (threadIdx.x < F) {
    shs[threadIdx.x] = shift[threadIdx.x];
    scs[threadIdx.x] = scale[threadIdx.x];
  }
  __syncthreads();
  int j = threadIdx.x & 63;
  int wave = (blockIdx.x * blockDim.x + threadIdx.x) >> 6;
  int nwaves = (gridDim.x * blockDim.x) >> 6;
  for (int v = wave; v < n; v += nwaves) {
    float xv = 0.f;
    if (j < F) xv = (x[(size_t)v * F + j] + shs[j]) * scs[j];
    float h = b1s[j];
#pragma unroll
    for (int f = 0; f < F; ++f) {
      float xf = __shfl(xv, f, 64);
      h += xf * W1s[f * 64 + j];
    }
    h = fmaxf(h, 0.f);
    float t = b2s[j];
#pragma unroll
    for (int k = 0; k < 64; ++k) {
      float hk = __shfl(h, k, 64);
      t += hk * W2s[k * 64 + j];
    }
    t = fmaxf(t, 0.f);
    if (bi) t += bi[v] * bWs[j];
    out[(size_t)v * 64 + j] = t;
  }
}

// ---------------- Fused SAGE: out = relu(mean(src[neigh]) @ Wl + bl + dstx @ Wr) ----------------

__global__ __launch_bounds__(256) void sage_kernel(
    const float* __restrict__ src, const float* __restrict__ dstx,
    const int* __restrict__ off, const int* __restrict__ adj,
    const float* __restrict__ Wl, const float* __restrict__ bl,
    const float* __restrict__ Wr, float* __restrict__ out, int n) {
  __shared__ float Wls[64 * 64];
  __shared__ float Wrs[64 * 64];
  __shared__ float bls[64];
  for (int i = threadIdx.x; i < 64 * 64; i += blockDim.x) {
    Wls[i] = Wl[i];
    Wrs[i] = Wr[i];
  }
  if (threadIdx.x < 64) bls[threadIdx.x] = bl[threadIdx.x];
  __syncthreads();
  int j = threadIdx.x & 63;
  int wave = (blockIdx.x * blockDim.x + threadIdx.x) >> 6;
  int nwaves = (gridDim.x * blockDim.x) >> 6;
  for (int v = wave; v < n; v += nwaves) {
    int s0 = off[v], s1 = off[v + 1];
    float acc = 0.f;
    for (int i = s0; i < s1; ++i) {
      int u = adj[i];
      acc += src[(size_t)u * 64 + j];
    }
    int deg = s1 - s0;
    float mean = (deg > 0) ? acc / (float)deg : 0.f;
    float xd = dstx[(size_t)v * 64 + j];
    float t = bls[j];
#pragma unroll
    for (int k = 0; k < 64; ++k) {
      float mk = __shfl(mean, k, 64);
      float xk = __shfl(xd, k, 64);
      t += mk * Wls[k * 64 + j] + xk * Wrs[k * 64 + j];
    }
    out[(size_t)v * 64 + j] = fmaxf(t, 0.f);
  }
}

// ---------------- host ----------------

extern "C" void kernel_launch(void* const* d_in, const int* in_sizes, int n_in,
                              void* d_out, int out_size, void* d_ws, size_t ws_size,
                              hipStream_t stream) {
  const float* cons_x = (const float*)d_in[0];
  const float* var_x  = (const float*)d_in[1];
  const int*   eidx   = (const int*)d_in[2];
  // d_in[3] edge_attr: unused by the reference output
  const float* bi     = (const float*)d_in[4];
  const float* c_sh   = (const float*)d_in[5];
  const float* c_sc   = (const float*)d_in[6];
  const float* v_sh   = (const float*)d_in[7];
  const float* v_sc   = (const float*)d_in[8];
  // d_in[9], d_in[10] edge pn: unused
  const float* cW1 = (const float*)d_in[11];
  const float* cb1 = (const float*)d_in[12];
  const float* cW2 = (const float*)d_in[13];
  const float* cb2 = (const float*)d_in[14];
  const float* vW1 = (const float*)d_in[15];
  const float* vb1 = (const float*)d_in[16];
  const float* vW2 = (const float*)d_in[17];
  const float* vb2 = (const float*)d_in[18];
  const float* bW  = (const float*)d_in[19];
  const float* Wl_cv = (const float*)d_in[20];
  const float* bl_cv = (const float*)d_in[21];
  const float* Wr_cv = (const float*)d_in[22];
  const float* Wl_vc = (const float*)d_in[23];
  const float* bl_vc = (const float*)d_in[24];
  const float* Wr_vc = (const float*)d_in[25];

  const int* row = eidx;           // [E] constraint index per edge
  const int* col = eidx + N_EDGE;  // [E] variable index per edge

  char* ws = (char*)d_ws;
  size_t o = 0;
  auto alloc = [&](size_t bytes) {
    char* p = ws + o;
    o = (o + bytes + 255) & ~(size_t)255;
    return p;
  };
  int* offV = (int*)alloc((N_VAR + 1) * sizeof(int));
  int* curV = (int*)alloc((N_VAR + 1) * sizeof(int));
  int* offC = (int*)alloc((N_CONS + 1) * sizeof(int));
  int* curC = (int*)alloc((N_CONS + 1) * sizeof(int));
  int* adjV = (int*)alloc((size_t)N_EDGE * sizeof(int));
  int* adjC = (int*)alloc((size_t)N_EDGE * sizeof(int));
  float* consE = (float*)alloc((size_t)N_CONS * EMB * sizeof(float));
  float* varE  = (float*)alloc((size_t)N_VAR * EMB * sizeof(float));
  float* cons1 = (float*)alloc((size_t)N_CONS * EMB * sizeof(float));
  float* var1  = (float*)d_out;  // layer-0 var output lives in d_out

  hipMemsetAsync(offV, 0, (N_VAR + 1) * sizeof(int), stream);
  hipMemsetAsync(offC, 0, (N_CONS + 1) * sizeof(int), stream);

  count_deg<<<2048, 256, 0, stream>>>(row, col, offV, offC, N_EDGE);
  scan2<<<2, 256, 0, stream>>>(offV, N_VAR, offC, N_CONS);
  hipMemcpyAsync(curV, offV, (N_VAR + 1) * sizeof(int), hipMemcpyDeviceToDevice, stream);
  hipMemcpyAsync(curC, offC, (N_CONS + 1) * sizeof(int), hipMemcpyDeviceToDevice, stream);
  scatter_adj<<<2048, 256, 0, stream>>>(row, col, curV, curC, adjV, adjC, N_EDGE);

  embed_kernel<5><<<1024, 256, 0, stream>>>(cons_x, c_sh, c_sc, cW1, cb1, cW2,
                                            cb2, nullptr, nullptr, consE, N_CONS);
  embed_kernel<19><<<2048, 256, 0, stream>>>(var_x, v_sh, v_sc, vW1, vb1, vW2,
                                             vb2, bi, bW, varE, N_VAR);

  // layer 0: new_var (cons->var) into d_out, new_cons (var->cons) into cons1
  sage_kernel<<<2048, 256, 0, stream>>>(consE, varE, offV, adjV, Wl_cv, bl_cv,
                                        Wr_cv, var1, N_VAR);
  sage_kernel<<<2048, 256, 0, stream>>>(varE, consE, offC, adjC, Wl_vc, bl_vc,
                                        Wr_vc, cons1, N_CONS);
  // layer 1: only new_var is needed (output); in-place own-row update of d_out
  sage_kernel<<<2048, 256, 0, stream>>>(cons1, var1, offV, adjV, Wl_cv + 4096,
                                        bl_cv + 64, Wr_cv + 4096, var1, N_VAR);
}

// Round 2
// 1157.442 us; speedup vs baseline: 2.7873x; 2.7873x over previous
//
#include <hip/hip_runtime.h>

#define N_CONS 100000
#define N_VAR  200000
#define N_TOT  (N_CONS + N_VAR)
#define N_EDGE 2000000
#define EMB 64
#define SCAN_NB 293  // ceil(300000/1024)

// ---------------- CSR build (combined: [0,N_VAR) var-dst, [N_VAR,N_TOT) cons-dst) ----------------

__global__ __launch_bounds__(256) void count_deg(const int* __restrict__ row,
                                                 const int* __restrict__ col,
                                                 int* __restrict__ deg, int E) {
  int stride = gridDim.x * blockDim.x;
  for (int e = blockIdx.x * blockDim.x + threadIdx.x; e < E; e += stride) {
    atomicAdd(&deg[col[e]], 1);
    atomicAdd(&deg[N_VAR + row[e]], 1);
  }
}

// S1: per-block (1024 elems) sums
__global__ __launch_bounds__(256) void scan_s1(const int* __restrict__ deg,
                                               int* __restrict__ bs) {
  __shared__ int s[256];
  int t = threadIdx.x;
  const int4* d4 = (const int4*)(deg + blockIdx.x * 1024);
  int4 v = d4[t];
  s[t] = v.x + v.y + v.z + v.w;
  __syncthreads();
  for (int d = 1; d < 256; d <<= 1) {
    int x = (t >= d) ? s[t - d] : 0;
    __syncthreads();
    s[t] += x;
    __syncthreads();
  }
  if (t == 255) bs[blockIdx.x] = s[255];
}

// S2: scan block sums (single block, 512 threads), write total to off[N_TOT]
__global__ __launch_bounds__(512) void scan_s2(int* __restrict__ bs,
                                               int* __restrict__ off) {
  __shared__ int s[512];
  int t = threadIdx.x;
  int v = (t < SCAN_NB) ? bs[t] : 0;
  s[t] = v;
  __syncthreads();
  for (int d = 1; d < 512; d <<= 1) {
    int x = (t >= d) ? s[t - d] : 0;
    __syncthreads();
    s[t] += x;
    __syncthreads();
  }
  if (t < SCAN_NB) bs[t] = s[t] - v;  // exclusive
  if (t == 511) off[N_TOT] = s[511];
}

// S3: local exclusive scan + block offset; writes off[] and cur[]
__global__ __launch_bounds__(256) void scan_s3(const int* __restrict__ deg,
                                               const int* __restrict__ bs,
                                               int* __restrict__ off,
                                               int* __restrict__ cur) {
  __shared__ int s[256];
  int t = threadIdx.x;
  int base = blockIdx.x * 1024;
  const int4* d4 = (const int4*)(deg + base);
  int4 v = d4[t];
  int sum = v.x + v.y + v.z + v.w;
  s[t] = sum;
  __syncthreads();
  for (int d = 1; d < 256; d <<= 1) {
    int x = (t >= d) ? s[t - d] : 0;
    __syncthreads();
    s[t] += x;
    __syncthreads();
  }
  int run = bs[blockIdx.x] + s[t] - sum;
  int i = base + t * 4;
  int vals[4] = {v.x, v.y, v.z, v.w};
#pragma unroll
  for (int q = 0; q < 4; ++q) {
    off[i + q] = run;
    cur[i + q] = run;
    run += vals[q];
  }
}

__global__ __launch_bounds__(256) void scatter_adj(const int* __restrict__ row,
                                                   const int* __restrict__ col,
                                                   int* __restrict__ cur,
                                                   int* __restrict__ adj, int E) {
  int stride = gridDim.x * blockDim.x;
  for (int e = blockIdx.x * blockDim.x + threadIdx.x; e < E; e += stride) {
    int r = row[e], c = col[e];
    int p = atomicAdd(&cur[c], 1);
    adj[p] = r;
    int q = atomicAdd(&cur[N_VAR + r], 1);
    adj[q] = c;
  }
}

// ---------------- Embedding MLP ----------------

template <int F>
__global__ __launch_bounds__(256) void embed_kernel(
    const float* __restrict__ x, const float* __restrict__ shift,
    const float* __restrict__ scale, const float* __restrict__ W1,
    const float* __restrict__ b1, const float* __restrict__ W2,
    const float* __restrict__ b2, const float* __restrict__ bi,
    const float* __restrict__ bW, float* __restrict__ out, int n) {
  __shared__ float W1s[F * 64];
  __shared__ float W2s[64 * 64];
  __shared__ float b1s[64], b2s[64], bWs[64];
  __shared__ float shs[32], scs[32];
  for (int i = threadIdx.x; i < F * 64; i += blockDim.x) W1s[i] = W1[i];
  for (int i = threadIdx.x; i < 64 * 64; i += blockDim.x) W2s[i] = W2[i];
  if (threadIdx.x < 64) {
    b1s[threadIdx.x] = b1[threadIdx.x];
    b2s[threadIdx.x] = b2[threadIdx.x];
    bWs[threadIdx.x] = bW ? bW[threadIdx.x] : 0.f;
  }
  if (threadIdx.x < F) {
    shs[threadIdx.x] = shift[threadIdx.x];
    scs[threadIdx.x] = scale[threadIdx.x];
  }
  __syncthreads();
  int j = threadIdx.x & 63;
  int wave = (blockIdx.x * blockDim.x + threadIdx.x) >> 6;
  int nwaves = (gridDim.x * blockDim.x) >> 6;
  for (int v = wave; v < n; v += nwaves) {
    float xv = 0.f;
    if (j < F) xv = (x[(size_t)v * F + j] + shs[j]) * scs[j];
    float h = b1s[j];
#pragma unroll
    for (int f = 0; f < F; ++f) {
      float xf = __shfl(xv, f, 64);
      h += xf * W1s[f * 64 + j];
    }
    h = fmaxf(h, 0.f);
    float t = b2s[j];
#pragma unroll
    for (int k = 0; k < 64; ++k) {
      float hk = __shfl(h, k, 64);
      t += hk * W2s[k * 64 + j];
    }
    t = fmaxf(t, 0.f);
    if (bi) t += bi[v] * bWs[j];
    out[(size_t)v * 64 + j] = t;
  }
}

// ---------------- Aggregation: mean over CSR neighbors (16 lanes/node, float4) ----------------

__global__ __launch_bounds__(256) void aggregate_kernel(
    const float4* __restrict__ src, const int* __restrict__ off,
    const int* __restrict__ adj, float4* __restrict__ mean, int n) {
  int slot = (blockIdx.x * blockDim.x + threadIdx.x) >> 4;
  int lane = threadIdx.x & 15;
  int nslots = (gridDim.x * blockDim.x) >> 4;
  for (int v = slot; v < n; v += nslots) {
    int s0 = off[v], s1 = off[v + 1];
    float ax = 0.f, ay = 0.f, az = 0.f, aw = 0.f;
    int i = s0;
    for (; i + 2 <= s1; i += 2) {
      int u0 = adj[i], u1 = adj[i + 1];
      float4 a = src[(size_t)u0 * 16 + lane];
      float4 b = src[(size_t)u1 * 16 + lane];
      ax += a.x + b.x;
      ay += a.y + b.y;
      az += a.z + b.z;
      aw += a.w + b.w;
    }
    if (i < s1) {
      int u0 = adj[i];
      float4 a = src[(size_t)u0 * 16 + lane];
      ax += a.x;
      ay += a.y;
      az += a.z;
      aw += a.w;
    }
    int deg = s1 - s0;
    float inv = (deg > 0) ? 1.f / (float)deg : 0.f;
    mean[(size_t)v * 16 + lane] = make_float4(ax * inv, ay * inv, az * inv, aw * inv);
  }
}

// ---------------- SAGE dense: out = relu(mean @ Wl + bl + dst @ Wr), 64x64 tile ----------------

__global__ __launch_bounds__(256) void sage_mm(
    const float* __restrict__ mean, const float* __restrict__ dstx,
    const float* __restrict__ Wl, const float* __restrict__ bl,
    const float* __restrict__ Wr, float* __restrict__ out, int n) {
  __shared__ float Xs[64][68];
  __shared__ float Ws[64][64];
  __shared__ float bls[64];
  int t = threadIdx.x;
  int jt = t & 15;
  int vt = t >> 4;
  int v0 = blockIdx.x * 64;
  if (t < 64) bls[t] = bl[t];
  float c[4][4] = {};

  auto stage = [&](const float* Xg, const float* Wg) {
#pragma unroll
    for (int r = 0; r < 4; ++r) {
      int idx = t + 256 * r;
      int rowi = idx >> 4, f4 = idx & 15;
      int v = v0 + rowi;
      float4 val = (v < n) ? ((const float4*)Xg)[(size_t)v * 16 + f4]
                           : make_float4(0.f, 0.f, 0.f, 0.f);
      *(float4*)&Xs[rowi][f4 * 4] = val;
      ((float4*)Ws)[idx] = ((const float4*)Wg)[idx];
    }
  };
  auto compute = [&]() {
#pragma unroll 4
    for (int k4 = 0; k4 < 16; ++k4) {
      float4 xv[4], wv[4];
#pragma unroll
      for (int i = 0; i < 4; ++i) xv[i] = *(const float4*)&Xs[vt * 4 + i][k4 * 4];
#pragma unroll
      for (int kk = 0; kk < 4; ++kk) wv[kk] = *(const float4*)&Ws[k4 * 4 + kk][jt * 4];
#pragma unroll
      for (int i = 0; i < 4; ++i) {
        c[i][0] += xv[i].x * wv[0].x + xv[i].y * wv[1].x + xv[i].z * wv[2].x + xv[i].w * wv[3].x;
        c[i][1] += xv[i].x * wv[0].y + xv[i].y * wv[1].y + xv[i].z * wv[2].y + xv[i].w * wv[3].y;
        c[i][2] += xv[i].x * wv[0].z + xv[i].y * wv[1].z + xv[i].z * wv[2].z + xv[i].w * wv[3].z;
        c[i][3] += xv[i].x * wv[0].w + xv[i].y * wv[1].w + xv[i].z * wv[2].w + xv[i].w * wv[3].w;
      }
    }
  };

  stage(mean, Wl);
  __syncthreads();
  compute();
  __syncthreads();
  stage(dstx, Wr);
  __syncthreads();
  compute();

#pragma unroll
  for (int i = 0; i < 4; ++i) {
    int v = v0 + vt * 4 + i;
    if (v < n) {
      float4 o;
      o.x = fmaxf(c[i][0] + bls[jt * 4 + 0], 0.f);
      o.y = fmaxf(c[i][1] + bls[jt * 4 + 1], 0.f);
      o.z = fmaxf(c[i][2] + bls[jt * 4 + 2], 0.f);
      o.w = fmaxf(c[i][3] + bls[jt * 4 + 3], 0.f);
      *(float4*)&out[(size_t)v * 64 + jt * 4] = o;
    }
  }
}

// ---------------- host ----------------

extern "C" void kernel_launch(void* const* d_in, const int* in_sizes, int n_in,
                              void* d_out, int out_size, void* d_ws, size_t ws_size,
                              hipStream_t stream) {
  const float* cons_x = (const float*)d_in[0];
  const float* var_x  = (const float*)d_in[1];
  const int*   eidx   = (const int*)d_in[2];
  const float* bi     = (const float*)d_in[4];
  const float* c_sh   = (const float*)d_in[5];
  const float* c_sc   = (const float*)d_in[6];
  const float* v_sh   = (const float*)d_in[7];
  const float* v_sc   = (const float*)d_in[8];
  const float* cW1 = (const float*)d_in[11];
  const float* cb1 = (const float*)d_in[12];
  const float* cW2 = (const float*)d_in[13];
  const float* cb2 = (const float*)d_in[14];
  const float* vW1 = (const float*)d_in[15];
  const float* vb1 = (const float*)d_in[16];
  const float* vW2 = (const float*)d_in[17];
  const float* vb2 = (const float*)d_in[18];
  const float* bW  = (const float*)d_in[19];
  const float* Wl_cv = (const float*)d_in[20];
  const float* bl_cv = (const float*)d_in[21];
  const float* Wr_cv = (const float*)d_in[22];
  const float* Wl_vc = (const float*)d_in[23];
  const float* bl_vc = (const float*)d_in[24];
  const float* Wr_vc = (const float*)d_in[25];

  const int* row = eidx;           // [E] constraint index per edge
  const int* col = eidx + N_EDGE;  // [E] variable index per edge

  char* ws = (char*)d_ws;
  size_t o = 0;
  auto alloc = [&](size_t bytes) {
    char* p = ws + o;
    o = (o + bytes + 255) & ~(size_t)255;
    return p;
  };
  const int SCAN_PAD = SCAN_NB * 1024;  // 300032
  int* off = (int*)alloc((SCAN_PAD + 1) * sizeof(int));
  int* cur = (int*)alloc(SCAN_PAD * sizeof(int));
  int* bs  = (int*)alloc(512 * sizeof(int));
  int* adj = (int*)alloc((size_t)2 * N_EDGE * sizeof(int));
  float* consE = (float*)alloc((size_t)N_CONS * EMB * sizeof(float));
  float* varE  = (float*)alloc((size_t)N_VAR * EMB * sizeof(float));
  float* meanb = (float*)alloc((size_t)N_VAR * EMB * sizeof(float));  // shared mean buffer
  float* var1  = (float*)d_out;

  hipMemsetAsync(cur, 0, SCAN_PAD * sizeof(int), stream);

  count_deg<<<2048, 256, 0, stream>>>(row, col, cur, N_EDGE);
  scan_s1<<<SCAN_NB, 256, 0, stream>>>(cur, bs);
  scan_s2<<<1, 512, 0, stream>>>(bs, off);
  scan_s3<<<SCAN_NB, 256, 0, stream>>>(cur, bs, off, cur);
  scatter_adj<<<2048, 256, 0, stream>>>(row, col, cur, adj, N_EDGE);

  embed_kernel<5><<<1024, 256, 0, stream>>>(cons_x, c_sh, c_sc, cW1, cb1, cW2,
                                            cb2, nullptr, nullptr, consE, N_CONS);
  embed_kernel<19><<<2048, 256, 0, stream>>>(var_x, v_sh, v_sc, vW1, vb1, vW2,
                                             vb2, bi, bW, varE, N_VAR);

  // layer 0, var side: mean over cons neighbors -> d_out
  aggregate_kernel<<<2048, 256, 0, stream>>>((const float4*)consE, off, adj,
                                             (float4*)meanb, N_VAR);
  sage_mm<<<(N_VAR + 63) / 64, 256, 0, stream>>>(meanb, varE, Wl_cv, bl_cv,
                                                 Wr_cv, var1, N_VAR);
  // layer 0, cons side: mean over var neighbors -> consE (in-place dst ok)
  aggregate_kernel<<<2048, 256, 0, stream>>>((const float4*)varE, off + N_VAR,
                                             adj, (float4*)meanb, N_CONS);
  sage_mm<<<(N_CONS + 63) / 64, 256, 0, stream>>>(meanb, consE, Wl_vc, bl_vc,
                                                  Wr_vc, consE, N_CONS);
  // layer 1, var side only (output); in-place dst = d_out
  aggregate_kernel<<<2048, 256, 0, stream>>>((const float4*)consE, off, adj,
                                             (float4*)meanb, N_VAR);
  sage_mm<<<(N_VAR + 63) / 64, 256, 0, stream>>>(meanb, var1, Wl_cv + 4096,
                                                 bl_cv + 64, Wr_cv + 4096, var1,
                                                 N_VAR);
}

// Round 3
// 728.573 us; speedup vs baseline: 4.4281x; 1.5886x over previous
//
#include <hip/hip_runtime.h>

#define N_CONS 100000
#define N_VAR  200000
#define N_TOT  (N_CONS + N_VAR)
#define N_EDGE 2000000
#define EMB 64

#define VSH 10
#define NBV 196   // ceil(200000/1024)
#define CAPV 12288
#define CSH 9
#define NBC 196   // ceil(100000/512)
#define CAPC 12288

// ---------------- CSR build: bucketed counting sort ----------------

__global__ __launch_bounds__(256) void csr_init(int* __restrict__ gcurV,
                                                int* __restrict__ gcurC,
                                                int* __restrict__ off) {
  int t = threadIdx.x;
  if (t < NBV) gcurV[t] = t * CAPV;
  if (t < NBC) gcurC[t] = t * CAPC;
  if (t == 0) off[N_TOT] = 2 * N_EDGE;
}

// Pass 1: per-block LDS histogram over buckets, reserve ranges, write packed pairs.
__global__ __launch_bounds__(256) void bucket_scatter(
    const int* __restrict__ row, const int* __restrict__ col,
    int* __restrict__ gcurV, int* __restrict__ gcurC,
    int* __restrict__ pairV, int* __restrict__ pairC) {
  __shared__ int hV[NBV];
  __shared__ int hC[NBC];
  int tid = threadIdx.x;
  int chunk = (N_EDGE + gridDim.x - 1) / gridDim.x;
  int lo = blockIdx.x * chunk;
  int hi = min(N_EDGE, lo + chunk);
  for (int i = tid; i < NBV; i += 256) hV[i] = 0;
  for (int i = tid; i < NBC; i += 256) hC[i] = 0;
  __syncthreads();
  for (int e = lo + tid; e < hi; e += 256) {
    atomicAdd(&hV[col[e] >> VSH], 1);
    atomicAdd(&hC[row[e] >> CSH], 1);
  }
  __syncthreads();
  for (int i = tid; i < NBV; i += 256) {
    int c = hV[i];
    hV[i] = c ? atomicAdd(&gcurV[i], c) : 0;
  }
  for (int i = tid; i < NBC; i += 256) {
    int c = hC[i];
    hC[i] = c ? atomicAdd(&gcurC[i], c) : 0;
  }
  __syncthreads();
  for (int e = lo + tid; e < hi; e += 256) {
    int r = row[e], c = col[e];
    int p = atomicAdd(&hV[c >> VSH], 1);
    pairV[p] = (r << VSH) | (c & ((1 << VSH) - 1));
    int q = atomicAdd(&hC[r >> CSH], 1);
    pairC[q] = (c << CSH) | (r & ((1 << CSH) - 1));
  }
}

// Pass 2: scan bucket counts -> exact CSR bucket bases.
__global__ __launch_bounds__(256) void bucket_scan(const int* __restrict__ gcurV,
                                                   const int* __restrict__ gcurC,
                                                   int* __restrict__ ebaseV,
                                                   int* __restrict__ ebaseC) {
  __shared__ int s[256];
  int t = threadIdx.x;
  int v = (t < NBV) ? (gcurV[t] - t * CAPV) : 0;
  s[t] = v;
  __syncthreads();
  for (int d = 1; d < 256; d <<= 1) {
    int x = (t >= d) ? s[t - d] : 0;
    __syncthreads();
    s[t] += x;
    __syncthreads();
  }
  if (t < NBV) ebaseV[t] = s[t] - v;
  if (t == NBV - 1) ebaseV[NBV] = s[t];
  __syncthreads();
  int c = (t < NBC) ? (gcurC[t] - t * CAPC) : 0;
  s[t] = c;
  __syncthreads();
  for (int d = 1; d < 256; d <<= 1) {
    int x = (t >= d) ? s[t - d] : 0;
    __syncthreads();
    s[t] += x;
    __syncthreads();
  }
  if (t < NBC) ebaseC[t] = s[t] - c;
  if (t == NBC - 1) ebaseC[NBC] = s[t];
}

// Pass 3: per bucket, build per-node offsets (LDS scan) and scatter adj locally.
__global__ __launch_bounds__(256) void local_csr(
    const int* __restrict__ pairV, const int* __restrict__ pairC,
    const int* __restrict__ ebaseV, const int* __restrict__ ebaseC,
    int* __restrict__ off, int* __restrict__ adj) {
  __shared__ int cnt[1024];
  __shared__ int cur[1024];
  __shared__ int s[256];
  int tid = threadIdx.x;
  int b = blockIdx.x;
  const int* pairs;
  int m, obase, nn, sh;
  int* offp;
  if (b < NBV) {
    pairs = pairV + (size_t)b * CAPV;
    m = ebaseV[b + 1] - ebaseV[b];
    obase = ebaseV[b];
    nn = min(1024, N_VAR - (b << 10));
    sh = VSH;
    offp = off + (b << 10);
  } else {
    int bb = b - NBV;
    pairs = pairC + (size_t)bb * CAPC;
    m = ebaseC[bb + 1] - ebaseC[bb];
    obase = N_EDGE + ebaseC[bb];
    nn = min(512, N_CONS - (bb << 9));
    sh = CSH;
    offp = off + N_VAR + (bb << 9);
  }
  int mask = (1 << sh) - 1;
  for (int i = tid; i < 1024; i += 256) cnt[i] = 0;
  __syncthreads();
  for (int k = tid; k < m; k += 256) atomicAdd(&cnt[pairs[k] & mask], 1);
  __syncthreads();
  int i0 = tid * 4;
  int c0 = cnt[i0], c1 = cnt[i0 + 1], c2 = cnt[i0 + 2], c3 = cnt[i0 + 3];
  int sum = c0 + c1 + c2 + c3;
  s[tid] = sum;
  __syncthreads();
  for (int d = 1; d < 256; d <<= 1) {
    int x = (tid >= d) ? s[tid - d] : 0;
    __syncthreads();
    s[tid] += x;
    __syncthreads();
  }
  int run = obase + s[tid] - sum;
  int vals[4] = {c0, c1, c2, c3};
#pragma unroll
  for (int q = 0; q < 4; ++q) {
    int i = i0 + q;
    cur[i] = run;
    if (i < nn) offp[i] = run;
    run += vals[q];
  }
  __syncthreads();
  for (int k = tid; k < m; k += 256) {
    int pr = pairs[k];
    int p = atomicAdd(&cur[pr & mask], 1);
    adj[p] = pr >> sh;
  }
}

// ---------------- Embedding MLP ----------------

template <int F>
__global__ __launch_bounds__(256) void embed_kernel(
    const float* __restrict__ x, const float* __restrict__ shift,
    const float* __restrict__ scale, const float* __restrict__ W1,
    const float* __restrict__ b1, const float* __restrict__ W2,
    const float* __restrict__ b2, const float* __restrict__ bi,
    const float* __restrict__ bW, float* __restrict__ out, int n) {
  __shared__ float W1s[F * 64];
  __shared__ float W2s[64 * 64];
  __shared__ float b1s[64], b2s[64], bWs[64];
  __shared__ float shs[32], scs[32];
  for (int i = threadIdx.x; i < F * 64; i += blockDim.x) W1s[i] = W1[i];
  for (int i = threadIdx.x; i < 64 * 64; i += blockDim.x) W2s[i] = W2[i];
  if (threadIdx.x < 64) {
    b1s[threadIdx.x] = b1[threadIdx.x];
    b2s[threadIdx.x] = b2[threadIdx.x];
    bWs[threadIdx.x] = bW ? bW[threadIdx.x] : 0.f;
  }
  if (threadIdx.x < F) {
    shs[threadIdx.x] = shift[threadIdx.x];
    scs[threadIdx.x] = scale[threadIdx.x];
  }
  __syncthreads();
  int j = threadIdx.x & 63;
  int wave = (blockIdx.x * blockDim.x + threadIdx.x) >> 6;
  int nwaves = (gridDim.x * blockDim.x) >> 6;
  for (int v = wave; v < n; v += nwaves) {
    float xv = 0.f;
    if (j < F) xv = (x[(size_t)v * F + j] + shs[j]) * scs[j];
    float h = b1s[j];
#pragma unroll
    for (int f = 0; f < F; ++f) {
      float xf = __shfl(xv, f, 64);
      h += xf * W1s[f * 64 + j];
    }
    h = fmaxf(h, 0.f);
    float t = b2s[j];
#pragma unroll
    for (int k = 0; k < 64; ++k) {
      float hk = __shfl(h, k, 64);
      t += hk * W2s[k * 64 + j];
    }
    t = fmaxf(t, 0.f);
    if (bi) t += bi[v] * bWs[j];
    out[(size_t)v * 64 + j] = t;
  }
}

// ---------------- Aggregation: mean over CSR neighbors (16 lanes/node, float4) ----------------

__global__ __launch_bounds__(256) void aggregate_kernel(
    const float4* __restrict__ src, const int* __restrict__ off,
    const int* __restrict__ adj, float4* __restrict__ mean, int n) {
  int slot = (blockIdx.x * blockDim.x + threadIdx.x) >> 4;
  int lane = threadIdx.x & 15;
  int nslots = (gridDim.x * blockDim.x) >> 4;
  for (int v = slot; v < n; v += nslots) {
    int s0 = off[v], s1 = off[v + 1];
    float ax = 0.f, ay = 0.f, az = 0.f, aw = 0.f;
    int i = s0;
    for (; i + 2 <= s1; i += 2) {
      int u0 = adj[i], u1 = adj[i + 1];
      float4 a = src[(size_t)u0 * 16 + lane];
      float4 b = src[(size_t)u1 * 16 + lane];
      ax += a.x + b.x;
      ay += a.y + b.y;
      az += a.z + b.z;
      aw += a.w + b.w;
    }
    if (i < s1) {
      int u0 = adj[i];
      float4 a = src[(size_t)u0 * 16 + lane];
      ax += a.x;
      ay += a.y;
      az += a.z;
      aw += a.w;
    }
    int deg = s1 - s0;
    float inv = (deg > 0) ? 1.f / (float)deg : 0.f;
    mean[(size_t)v * 16 + lane] = make_float4(ax * inv, ay * inv, az * inv, aw * inv);
  }
}

// ---------------- SAGE dense: out = relu(mean @ Wl + bl + dst @ Wr), 64x64 tile ----------------

__global__ __launch_bounds__(256) void sage_mm(
    const float* __restrict__ mean, const float* __restrict__ dstx,
    const float* __restrict__ Wl, const float* __restrict__ bl,
    const float* __restrict__ Wr, float* __restrict__ out, int n) {
  __shared__ float Xs[64][68];
  __shared__ float Ws[64][64];
  __shared__ float bls[64];
  int t = threadIdx.x;
  int jt = t & 15;
  int vt = t >> 4;
  int v0 = blockIdx.x * 64;
  if (t < 64) bls[t] = bl[t];
  float c[4][4] = {};

  auto stage = [&](const float* Xg, const float* Wg) {
#pragma unroll
    for (int r = 0; r < 4; ++r) {
      int idx = t + 256 * r;
      int rowi = idx >> 4, f4 = idx & 15;
      int v = v0 + rowi;
      float4 val = (v < n) ? ((const float4*)Xg)[(size_t)v * 16 + f4]
                           : make_float4(0.f, 0.f, 0.f, 0.f);
      *(float4*)&Xs[rowi][f4 * 4] = val;
      ((float4*)Ws)[idx] = ((const float4*)Wg)[idx];
    }
  };
  auto compute = [&]() {
#pragma unroll 4
    for (int k4 = 0; k4 < 16; ++k4) {
      float4 xv[4], wv[4];
#pragma unroll
      for (int i = 0; i < 4; ++i) xv[i] = *(const float4*)&Xs[vt * 4 + i][k4 * 4];
#pragma unroll
      for (int kk = 0; kk < 4; ++kk) wv[kk] = *(const float4*)&Ws[k4 * 4 + kk][jt * 4];
#pragma unroll
      for (int i = 0; i < 4; ++i) {
        c[i][0] += xv[i].x * wv[0].x + xv[i].y * wv[1].x + xv[i].z * wv[2].x + xv[i].w * wv[3].x;
        c[i][1] += xv[i].x * wv[0].y + xv[i].y * wv[1].y + xv[i].z * wv[2].y + xv[i].w * wv[3].y;
        c[i][2] += xv[i].x * wv[0].z + xv[i].y * wv[1].z + xv[i].z * wv[2].z + xv[i].w * wv[3].z;
        c[i][3] += xv[i].x * wv[0].w + xv[i].y * wv[1].w + xv[i].z * wv[2].w + xv[i].w * wv[3].w;
      }
    }
  };

  stage(mean, Wl);
  __syncthreads();
  compute();
  __syncthreads();
  stage(dstx, Wr);
  __syncthreads();
  compute();

#pragma unroll
  for (int i = 0; i < 4; ++i) {
    int v = v0 + vt * 4 + i;
    if (v < n) {
      float4 o;
      o.x = fmaxf(c[i][0] + bls[jt * 4 + 0], 0.f);
      o.y = fmaxf(c[i][1] + bls[jt * 4 + 1], 0.f);
      o.z = fmaxf(c[i][2] + bls[jt * 4 + 2], 0.f);
      o.w = fmaxf(c[i][3] + bls[jt * 4 + 3], 0.f);
      *(float4*)&out[(size_t)v * 64 + jt * 4] = o;
    }
  }
}

// ---------------- host ----------------

extern "C" void kernel_launch(void* const* d_in, const int* in_sizes, int n_in,
                              void* d_out, int out_size, void* d_ws, size_t ws_size,
                              hipStream_t stream) {
  const float* cons_x = (const float*)d_in[0];
  const float* var_x  = (const float*)d_in[1];
  const int*   eidx   = (const int*)d_in[2];
  const float* bi     = (const float*)d_in[4];
  const float* c_sh   = (const float*)d_in[5];
  const float* c_sc   = (const float*)d_in[6];
  const float* v_sh   = (const float*)d_in[7];
  const float* v_sc   = (const float*)d_in[8];
  const float* cW1 = (const float*)d_in[11];
  const float* cb1 = (const float*)d_in[12];
  const float* cW2 = (const float*)d_in[13];
  const float* cb2 = (const float*)d_in[14];
  const float* vW1 = (const float*)d_in[15];
  const float* vb1 = (const float*)d_in[16];
  const float* vW2 = (const float*)d_in[17];
  const float* vb2 = (const float*)d_in[18];
  const float* bW  = (const float*)d_in[19];
  const float* Wl_cv = (const float*)d_in[20];
  const float* bl_cv = (const float*)d_in[21];
  const float* Wr_cv = (const float*)d_in[22];
  const float* Wl_vc = (const float*)d_in[23];
  const float* bl_vc = (const float*)d_in[24];
  const float* Wr_vc = (const float*)d_in[25];

  const int* row = eidx;           // [E] constraint index per edge
  const int* col = eidx + N_EDGE;  // [E] variable index per edge

  char* ws = (char*)d_ws;
  size_t o = 0;
  auto alloc = [&](size_t bytes) {
    char* p = ws + o;
    o = (o + bytes + 255) & ~(size_t)255;
    return p;
  };
  int* off    = (int*)alloc((N_TOT + 1) * sizeof(int));
  int* adj    = (int*)alloc((size_t)2 * N_EDGE * sizeof(int));
  int* pairV  = (int*)alloc((size_t)NBV * CAPV * sizeof(int));
  int* pairC  = (int*)alloc((size_t)NBC * CAPC * sizeof(int));
  int* gcurV  = (int*)alloc(256 * sizeof(int));
  int* gcurC  = (int*)alloc(256 * sizeof(int));
  int* ebaseV = (int*)alloc(256 * sizeof(int));
  int* ebaseC = (int*)alloc(256 * sizeof(int));
  float* consE = (float*)alloc((size_t)N_CONS * EMB * sizeof(float));
  float* varE  = (float*)alloc((size_t)N_VAR * EMB * sizeof(float));
  float* meanb = (float*)alloc((size_t)N_VAR * EMB * sizeof(float));
  float* var1  = (float*)d_out;

  csr_init<<<1, 256, 0, stream>>>(gcurV, gcurC, off);
  bucket_scatter<<<512, 256, 0, stream>>>(row, col, gcurV, gcurC, pairV, pairC);
  bucket_scan<<<1, 256, 0, stream>>>(gcurV, gcurC, ebaseV, ebaseC);
  local_csr<<<NBV + NBC, 256, 0, stream>>>(pairV, pairC, ebaseV, ebaseC, off, adj);

  embed_kernel<5><<<1024, 256, 0, stream>>>(cons_x, c_sh, c_sc, cW1, cb1, cW2,
                                            cb2, nullptr, nullptr, consE, N_CONS);
  embed_kernel<19><<<2048, 256, 0, stream>>>(var_x, v_sh, v_sc, vW1, vb1, vW2,
                                             vb2, bi, bW, varE, N_VAR);

  // layer 0, var side
  aggregate_kernel<<<2048, 256, 0, stream>>>((const float4*)consE, off, adj,
                                             (float4*)meanb, N_VAR);
  sage_mm<<<(N_VAR + 63) / 64, 256, 0, stream>>>(meanb, varE, Wl_cv, bl_cv,
                                                 Wr_cv, var1, N_VAR);
  // layer 0, cons side
  aggregate_kernel<<<2048, 256, 0, stream>>>((const float4*)varE, off + N_VAR,
                                             adj, (float4*)meanb, N_CONS);
  sage_mm<<<(N_CONS + 63) / 64, 256, 0, stream>>>(meanb, consE, Wl_vc, bl_vc,
                                                  Wr_vc, consE, N_CONS);
  // layer 1, var side only (output)
  aggregate_kernel<<<2048, 256, 0, stream>>>((const float4*)consE, off, adj,
                                             (float4*)meanb, N_VAR);
  sage_mm<<<(N_VAR + 63) / 64, 256, 0, stream>>>(meanb, var1, Wl_cv + 4096,
                                                 bl_cv + 64, Wr_cv + 4096, var1,
                                                 N_VAR);
}

// Round 4
// 522.540 us; speedup vs baseline: 6.1740x; 1.3943x over previous
//
#include <hip/hip_runtime.h>

#define N_CONS 100000
#define N_VAR  200000
#define N_TOT  (N_CONS + N_VAR)
#define N_EDGE 2000000
#define EMB 64

#define VSH 10
#define NBV 196   // ceil(200000/1024)
#define CAPV 12288
#define CSH 9
#define NBC 196   // ceil(100000/512)
#define CAPC 12288

// ---------------- CSR build: bucketed counting sort ----------------

__global__ __launch_bounds__(256) void csr_init(int* __restrict__ gcurV,
                                                int* __restrict__ gcurC,
                                                int* __restrict__ off) {
  int t = threadIdx.x;
  if (t < NBV) gcurV[t] = t * CAPV;
  if (t < NBC) gcurC[t] = t * CAPC;
  if (t == 0) off[N_TOT] = 2 * N_EDGE;
}

__global__ __launch_bounds__(256) void bucket_scatter(
    const int* __restrict__ row, const int* __restrict__ col,
    int* __restrict__ gcurV, int* __restrict__ gcurC,
    int* __restrict__ pairV, int* __restrict__ pairC) {
  __shared__ int hV[NBV];
  __shared__ int hC[NBC];
  int tid = threadIdx.x;
  int chunk = (N_EDGE + gridDim.x - 1) / gridDim.x;
  int lo = blockIdx.x * chunk;
  int hi = min(N_EDGE, lo + chunk);
  for (int i = tid; i < NBV; i += 256) hV[i] = 0;
  for (int i = tid; i < NBC; i += 256) hC[i] = 0;
  __syncthreads();
  for (int e = lo + tid; e < hi; e += 256) {
    atomicAdd(&hV[col[e] >> VSH], 1);
    atomicAdd(&hC[row[e] >> CSH], 1);
  }
  __syncthreads();
  for (int i = tid; i < NBV; i += 256) {
    int c = hV[i];
    hV[i] = c ? atomicAdd(&gcurV[i], c) : 0;
  }
  for (int i = tid; i < NBC; i += 256) {
    int c = hC[i];
    hC[i] = c ? atomicAdd(&gcurC[i], c) : 0;
  }
  __syncthreads();
  for (int e = lo + tid; e < hi; e += 256) {
    int r = row[e], c = col[e];
    int p = atomicAdd(&hV[c >> VSH], 1);
    pairV[p] = (r << VSH) | (c & ((1 << VSH) - 1));
    int q = atomicAdd(&hC[r >> CSH], 1);
    pairC[q] = (c << CSH) | (r & ((1 << CSH) - 1));
  }
}

__global__ __launch_bounds__(256) void bucket_scan(const int* __restrict__ gcurV,
                                                   const int* __restrict__ gcurC,
                                                   int* __restrict__ ebaseV,
                                                   int* __restrict__ ebaseC) {
  __shared__ int s[256];
  int t = threadIdx.x;
  int v = (t < NBV) ? (gcurV[t] - t * CAPV) : 0;
  s[t] = v;
  __syncthreads();
  for (int d = 1; d < 256; d <<= 1) {
    int x = (t >= d) ? s[t - d] : 0;
    __syncthreads();
    s[t] += x;
    __syncthreads();
  }
  if (t < NBV) ebaseV[t] = s[t] - v;
  if (t == NBV - 1) ebaseV[NBV] = s[t];
  __syncthreads();
  int c = (t < NBC) ? (gcurC[t] - t * CAPC) : 0;
  s[t] = c;
  __syncthreads();
  for (int d = 1; d < 256; d <<= 1) {
    int x = (t >= d) ? s[t - d] : 0;
    __syncthreads();
    s[t] += x;
    __syncthreads();
  }
  if (t < NBC) ebaseC[t] = s[t] - c;
  if (t == NBC - 1) ebaseC[NBC] = s[t];
}

__global__ __launch_bounds__(256) void local_csr(
    const int* __restrict__ pairV, const int* __restrict__ pairC,
    const int* __restrict__ ebaseV, const int* __restrict__ ebaseC,
    int* __restrict__ off, int* __restrict__ adj) {
  __shared__ int cnt[1024];
  __shared__ int cur[1024];
  __shared__ int s[256];
  int tid = threadIdx.x;
  int b = blockIdx.x;
  const int* pairs;
  int m, obase, nn, sh;
  int* offp;
  if (b < NBV) {
    pairs = pairV + (size_t)b * CAPV;
    m = ebaseV[b + 1] - ebaseV[b];
    obase = ebaseV[b];
    nn = min(1024, N_VAR - (b << 10));
    sh = VSH;
    offp = off + (b << 10);
  } else {
    int bb = b - NBV;
    pairs = pairC + (size_t)bb * CAPC;
    m = ebaseC[bb + 1] - ebaseC[bb];
    obase = N_EDGE + ebaseC[bb];
    nn = min(512, N_CONS - (bb << 9));
    sh = CSH;
    offp = off + N_VAR + (bb << 9);
  }
  int mask = (1 << sh) - 1;
  for (int i = tid; i < 1024; i += 256) cnt[i] = 0;
  __syncthreads();
  for (int k = tid; k < m; k += 256) atomicAdd(&cnt[pairs[k] & mask], 1);
  __syncthreads();
  int i0 = tid * 4;
  int c0 = cnt[i0], c1 = cnt[i0 + 1], c2 = cnt[i0 + 2], c3 = cnt[i0 + 3];
  int sum = c0 + c1 + c2 + c3;
  s[tid] = sum;
  __syncthreads();
  for (int d = 1; d < 256; d <<= 1) {
    int x = (tid >= d) ? s[tid - d] : 0;
    __syncthreads();
    s[tid] += x;
    __syncthreads();
  }
  int run = obase + s[tid] - sum;
  int vals[4] = {c0, c1, c2, c3};
#pragma unroll
  for (int q = 0; q < 4; ++q) {
    int i = i0 + q;
    cur[i] = run;
    if (i < nn) offp[i] = run;
    run += vals[q];
  }
  __syncthreads();
  for (int k = tid; k < m; k += 256) {
    int pr = pairs[k];
    int p = atomicAdd(&cur[pr & mask], 1);
    adj[p] = pr >> sh;
  }
}

// ---------------- Embedding as tiled GEMM: out = relu(relu(pn(x)@W1+b1)@W2+b2) [+ bi*bW] ----------------

template <int F>
__global__ __launch_bounds__(256) void embed_mm(
    const float* __restrict__ x, const float* __restrict__ shift,
    const float* __restrict__ scale, const float* __restrict__ W1,
    const float* __restrict__ b1, const float* __restrict__ W2,
    const float* __restrict__ b2, const float* __restrict__ bi,
    const float* __restrict__ bW, float* __restrict__ out, int n) {
  __shared__ float Xs[64 * F];
  __shared__ float W1s[F][64];
  __shared__ float Hs[64][68];
  __shared__ float W2s[64][64];
  __shared__ float b1s[64], b2s[64], bWs[64], bis[64];
  int t = threadIdx.x;
  int v0 = blockIdx.x * 64;
  // W1' = scale_k * W1[k][j]; b1' = b1 + sum_k shift*scale*W1
  for (int i = t; i < F * 64; i += 256) W1s[i / 64][i % 64] = W1[i] * scale[i / 64];
  for (int i = t; i < 64 * 64; i += 256) ((float*)W2s)[i] = W2[i];
  if (t < 64) {
    float acc = b1[t];
#pragma unroll
    for (int k = 0; k < F; ++k) acc += shift[k] * scale[k] * W1[k * 64 + t];
    b1s[t] = acc;
    b2s[t] = b2[t];
    bWs[t] = bW ? bW[t] : 0.f;
    bis[t] = (bi && v0 + t < n) ? bi[v0 + t] : 0.f;
  }
  int count = (min(n, v0 + 64) - v0) * F;
  for (int i = t; i < count; i += 256) Xs[i] = x[(size_t)v0 * F + i];
  __syncthreads();

  int jt = t & 15;
  int vt = t >> 4;
  // GEMM1: h = relu(X @ W1' + b1')
  float c[4][4] = {};
#pragma unroll
  for (int k = 0; k < F; ++k) {
    float w0 = W1s[k][jt * 4], w1 = W1s[k][jt * 4 + 1];
    float w2 = W1s[k][jt * 4 + 2], w3 = W1s[k][jt * 4 + 3];
#pragma unroll
    for (int i = 0; i < 4; ++i) {
      float xv = Xs[(vt * 4 + i) * F + k];
      c[i][0] += xv * w0;
      c[i][1] += xv * w1;
      c[i][2] += xv * w2;
      c[i][3] += xv * w3;
    }
  }
#pragma unroll
  for (int i = 0; i < 4; ++i)
#pragma unroll
    for (int q = 0; q < 4; ++q)
      Hs[vt * 4 + i][jt * 4 + q] = fmaxf(c[i][q] + b1s[jt * 4 + q], 0.f);
  __syncthreads();
  // GEMM2: out = relu(H @ W2 + b2) + bi*bW
  float d[4][4] = {};
#pragma unroll 4
  for (int k4 = 0; k4 < 16; ++k4) {
    float4 xv[4], wv[4];
#pragma unroll
    for (int i = 0; i < 4; ++i) xv[i] = *(const float4*)&Hs[vt * 4 + i][k4 * 4];
#pragma unroll
    for (int kk = 0; kk < 4; ++kk) wv[kk] = *(const float4*)&W2s[k4 * 4 + kk][jt * 4];
#pragma unroll
    for (int i = 0; i < 4; ++i) {
      d[i][0] += xv[i].x * wv[0].x + xv[i].y * wv[1].x + xv[i].z * wv[2].x + xv[i].w * wv[3].x;
      d[i][1] += xv[i].x * wv[0].y + xv[i].y * wv[1].y + xv[i].z * wv[2].y + xv[i].w * wv[3].y;
      d[i][2] += xv[i].x * wv[0].z + xv[i].y * wv[1].z + xv[i].z * wv[2].z + xv[i].w * wv[3].z;
      d[i][3] += xv[i].x * wv[0].w + xv[i].y * wv[1].w + xv[i].z * wv[2].w + xv[i].w * wv[3].w;
    }
  }
#pragma unroll
  for (int i = 0; i < 4; ++i) {
    int v = v0 + vt * 4 + i;
    if (v < n) {
      float bv = bis[vt * 4 + i];
      float4 o;
      o.x = fmaxf(d[i][0] + b2s[jt * 4 + 0], 0.f) + bv * bWs[jt * 4 + 0];
      o.y = fmaxf(d[i][1] + b2s[jt * 4 + 1], 0.f) + bv * bWs[jt * 4 + 1];
      o.z = fmaxf(d[i][2] + b2s[jt * 4 + 2], 0.f) + bv * bWs[jt * 4 + 2];
      o.w = fmaxf(d[i][3] + b2s[jt * 4 + 3], 0.f) + bv * bWs[jt * 4 + 3];
      *(float4*)&out[(size_t)v * 64 + jt * 4] = o;
    }
  }
}

// ---------------- Fused SAGE: gather-mean into LDS, then dual GEMM ----------------
// out = relu(mean(src[neigh]) @ Wl + bl + dstx @ Wr), 64-node tile per block

__global__ __launch_bounds__(256) void sage_fused(
    const float4* __restrict__ src, const float* __restrict__ dstx,
    const int* __restrict__ off, const int* __restrict__ adj,
    const float* __restrict__ Wl, const float* __restrict__ bl,
    const float* __restrict__ Wr, float* __restrict__ out, int n) {
  __shared__ float Hs[64][68];
  __shared__ float Ws[64][64];
  __shared__ float bls[64];
  int t = threadIdx.x;
  int v0 = blockIdx.x * 64;
  if (t < 64) bls[t] = bl[t];
  for (int i = t; i < 1024; i += 256) ((float4*)Ws)[i] = ((const float4*)Wl)[i];

  // Phase A: gather-mean into Hs (16 lanes/node, float4, unroll-2)
  int lane = t & 15;
  int g = t >> 4;
#pragma unroll
  for (int grp = 0; grp < 4; ++grp) {
    int r = grp * 16 + g;
    int v = v0 + r;
    float ax = 0.f, ay = 0.f, az = 0.f, aw = 0.f;
    if (v < n) {
      int s0 = off[v], s1 = off[v + 1];
      int i = s0;
      for (; i + 2 <= s1; i += 2) {
        float4 a = src[(size_t)adj[i] * 16 + lane];
        float4 b = src[(size_t)adj[i + 1] * 16 + lane];
        ax += a.x + b.x;
        ay += a.y + b.y;
        az += a.z + b.z;
        aw += a.w + b.w;
      }
      if (i < s1) {
        float4 a = src[(size_t)adj[i] * 16 + lane];
        ax += a.x;
        ay += a.y;
        az += a.z;
        aw += a.w;
      }
      int deg = s1 - s0;
      float inv = (deg > 0) ? 1.f / (float)deg : 0.f;
      ax *= inv;
      ay *= inv;
      az *= inv;
      aw *= inv;
    }
    *(float4*)&Hs[r][lane * 4] = make_float4(ax, ay, az, aw);
  }
  __syncthreads();

  int jt = t & 15;
  int vt = t >> 4;
  float c[4][4] = {};
  auto compute = [&]() {
#pragma unroll 4
    for (int k4 = 0; k4 < 16; ++k4) {
      float4 xv[4], wv[4];
#pragma unroll
      for (int i = 0; i < 4; ++i) xv[i] = *(const float4*)&Hs[vt * 4 + i][k4 * 4];
#pragma unroll
      for (int kk = 0; kk < 4; ++kk) wv[kk] = *(const float4*)&Ws[k4 * 4 + kk][jt * 4];
#pragma unroll
      for (int i = 0; i < 4; ++i) {
        c[i][0] += xv[i].x * wv[0].x + xv[i].y * wv[1].x + xv[i].z * wv[2].x + xv[i].w * wv[3].x;
        c[i][1] += xv[i].x * wv[0].y + xv[i].y * wv[1].y + xv[i].z * wv[2].y + xv[i].w * wv[3].y;
        c[i][2] += xv[i].x * wv[0].z + xv[i].y * wv[1].z + xv[i].z * wv[2].z + xv[i].w * wv[3].z;
        c[i][3] += xv[i].x * wv[0].w + xv[i].y * wv[1].w + xv[i].z * wv[2].w + xv[i].w * wv[3].w;
      }
    }
  };
  compute();  // mean @ Wl
  __syncthreads();
  // stage dstx tile + Wr
#pragma unroll
  for (int r = 0; r < 4; ++r) {
    int idx = t + 256 * r;
    int rowi = idx >> 4, f4 = idx & 15;
    int v = v0 + rowi;
    float4 val = (v < n) ? ((const float4*)dstx)[(size_t)v * 16 + f4]
                         : make_float4(0.f, 0.f, 0.f, 0.f);
    *(float4*)&Hs[rowi][f4 * 4] = val;
    ((float4*)Ws)[idx] = ((const float4*)Wr)[idx];
  }
  __syncthreads();
  compute();  // += dstx @ Wr

#pragma unroll
  for (int i = 0; i < 4; ++i) {
    int v = v0 + vt * 4 + i;
    if (v < n) {
      float4 o;
      o.x = fmaxf(c[i][0] + bls[jt * 4 + 0], 0.f);
      o.y = fmaxf(c[i][1] + bls[jt * 4 + 1], 0.f);
      o.z = fmaxf(c[i][2] + bls[jt * 4 + 2], 0.f);
      o.w = fmaxf(c[i][3] + bls[jt * 4 + 3], 0.f);
      *(float4*)&out[(size_t)v * 64 + jt * 4] = o;
    }
  }
}

// ---------------- host ----------------

extern "C" void kernel_launch(void* const* d_in, const int* in_sizes, int n_in,
                              void* d_out, int out_size, void* d_ws, size_t ws_size,
                              hipStream_t stream) {
  const float* cons_x = (const float*)d_in[0];
  const float* var_x  = (const float*)d_in[1];
  const int*   eidx   = (const int*)d_in[2];
  const float* bi     = (const float*)d_in[4];
  const float* c_sh   = (const float*)d_in[5];
  const float* c_sc   = (const float*)d_in[6];
  const float* v_sh   = (const float*)d_in[7];
  const float* v_sc   = (const float*)d_in[8];
  const float* cW1 = (const float*)d_in[11];
  const float* cb1 = (const float*)d_in[12];
  const float* cW2 = (const float*)d_in[13];
  const float* cb2 = (const float*)d_in[14];
  const float* vW1 = (const float*)d_in[15];
  const float* vb1 = (const float*)d_in[16];
  const float* vW2 = (const float*)d_in[17];
  const float* vb2 = (const float*)d_in[18];
  const float* bW  = (const float*)d_in[19];
  const float* Wl_cv = (const float*)d_in[20];
  const float* bl_cv = (const float*)d_in[21];
  const float* Wr_cv = (const float*)d_in[22];
  const float* Wl_vc = (const float*)d_in[23];
  const float* bl_vc = (const float*)d_in[24];
  const float* Wr_vc = (const float*)d_in[25];

  const int* row = eidx;           // [E] constraint index per edge
  const int* col = eidx + N_EDGE;  // [E] variable index per edge

  char* ws = (char*)d_ws;
  size_t o = 0;
  auto alloc = [&](size_t bytes) {
    char* p = ws + o;
    o = (o + bytes + 255) & ~(size_t)255;
    return p;
  };
  int* off    = (int*)alloc((N_TOT + 1) * sizeof(int));
  int* adj    = (int*)alloc((size_t)2 * N_EDGE * sizeof(int));
  int* pairV  = (int*)alloc((size_t)NBV * CAPV * sizeof(int));
  int* pairC  = (int*)alloc((size_t)NBC * CAPC * sizeof(int));
  int* gcurV  = (int*)alloc(256 * sizeof(int));
  int* gcurC  = (int*)alloc(256 * sizeof(int));
  int* ebaseV = (int*)alloc(256 * sizeof(int));
  int* ebaseC = (int*)alloc(256 * sizeof(int));
  float* consE = (float*)alloc((size_t)N_CONS * EMB * sizeof(float));
  float* varE  = (float*)alloc((size_t)N_VAR * EMB * sizeof(float));
  float* var1  = (float*)d_out;

  csr_init<<<1, 256, 0, stream>>>(gcurV, gcurC, off);
  bucket_scatter<<<512, 256, 0, stream>>>(row, col, gcurV, gcurC, pairV, pairC);
  bucket_scan<<<1, 256, 0, stream>>>(gcurV, gcurC, ebaseV, ebaseC);
  local_csr<<<NBV + NBC, 256, 0, stream>>>(pairV, pairC, ebaseV, ebaseC, off, adj);

  embed_mm<5><<<(N_CONS + 63) / 64, 256, 0, stream>>>(
      cons_x, c_sh, c_sc, cW1, cb1, cW2, cb2, nullptr, nullptr, consE, N_CONS);
  embed_mm<19><<<(N_VAR + 63) / 64, 256, 0, stream>>>(
      var_x, v_sh, v_sc, vW1, vb1, vW2, vb2, bi, bW, varE, N_VAR);

  // layer 0, var side: d_out = relu(mean_cons @ Wl_cv + bl + varE @ Wr_cv)
  sage_fused<<<(N_VAR + 63) / 64, 256, 0, stream>>>(
      (const float4*)consE, varE, off, adj, Wl_cv, bl_cv, Wr_cv, var1, N_VAR);
  // layer 0, cons side (in-place consE)
  sage_fused<<<(N_CONS + 63) / 64, 256, 0, stream>>>(
      (const float4*)varE, consE, off + N_VAR, adj, Wl_vc, bl_vc, Wr_vc, consE,
      N_CONS);
  // layer 1, var side only (in-place d_out)
  sage_fused<<<(N_VAR + 63) / 64, 256, 0, stream>>>(
      (const float4*)consE, var1, off, adj, Wl_cv + 4096, bl_cv + 64,
      Wr_cv + 4096, var1, N_VAR);
}